// Round 4
// baseline (6832.705 us; speedup 1.0000x reference)
//
#include <hip/hip_runtime.h>

typedef _Float16 f16;
typedef _Float16 f16x8 __attribute__((ext_vector_type(8)));
typedef _Float16 f16x4 __attribute__((ext_vector_type(4)));
typedef float f32x4 __attribute__((ext_vector_type(4)));

__device__ __forceinline__ f32x4 mfma16(f16x8 a, f16x8 b, f32x4 c) {
  return __builtin_amdgcn_mfma_f32_16x16x32_f16(a, b, c, 0, 0, 0);
}
__device__ __forceinline__ float sigm(float x) { return 1.0f / (1.0f + __expf(-x)); }
__device__ __forceinline__ float tanh_fast(float x) { return 1.0f - 2.0f / (__expf(2.0f * x) + 1.0f); }

// ---------------- workspace layout (bytes) ----------------
constexpr size_t OFF_PW0   = 0;                        // packed Whh L0 frags, 1.5MB
constexpr size_t OFF_PW1   = 1572864;                  // packed Whh L1 frags, 1.5MB
constexpr size_t OFF_WIH1  = 3145728;                  // plain f16 [1536][512], 1.5MB
constexpr size_t OFF_WLIN  = 4718592;                  // plain f16 [512][512], 0.5MB
constexpr size_t OFF_WP0   = 5242880;                  // layer0 Wih frags [96][64][8], 96KB
constexpr size_t OFF_XPAD  = 5341184;                  // [128][256][8] f16, 512KB
constexpr size_t OFF_CNT   = 5865472;                  // 2 x int[512] sync counters, 4KB
constexpr size_t OFF_Y0E   = 5869568;                  // [129][256][512] f16, 33.8MB (slot0=h0)
constexpr size_t OFF_Y1E   = 39686144;                 // [129][256][512] f16, 33.8MB
constexpr size_t OFF_GIU   = 73502720;                 // GIP f16 100.7MB, then U f32 64MB aliased
constexpr size_t OFF_DIAG  = 174166016;                // dsuf/de/du

// ---------------- prep: pack Whh into per-wave register-fragment order ----------------
// PW frag f = (jg*16 + kt)*3 + g  (jg 0..31, kt 0..15, g 0..2); [f][lane(64)][8 f16]
// content: row = g*512 + jg*16 + (lane&15); k = kt*32 + (lane>>4)*8
__global__ __launch_bounds__(256) void prep_pack_k(
    const float* __restrict__ Whh0, const float* __restrict__ Whh1,
    f16* __restrict__ P0, f16* __restrict__ P1)
{
  int idx = blockIdx.x * 256 + threadIdx.x;          // 0..196607
  const float* W = (idx < 98304) ? Whh0 : Whh1;
  f16* P = (idx < 98304) ? P0 : P1;
  int q = (idx < 98304) ? idx : idx - 98304;         // (98304 not pow2: subtract!)
  int lane = q & 63; int f = q >> 6;                 // f 0..1535
  int g = f % 3; int u = f / 3;                      // u 0..511
  int kt = u & 15; int jg = u >> 4;                  // jg 0..31
  int row = g * 512 + jg * 16 + (lane & 15);
  int k = kt * 32 + (lane >> 4) * 8;
  const float* src = W + (size_t)row * 512 + k;
  f16* dst = P + (size_t)q * 8;
#pragma unroll
  for (int c = 0; c < 8; ++c) dst[c] = (f16)src[c];
}

// ---------------- prep: weights, x packing, h0 slots, counter zeroing ----------------
__global__ __launch_bounds__(256) void prep_misc_k(
    const float* __restrict__ Wih1, const float* __restrict__ Wlin,
    const float* __restrict__ Wih0, const float* __restrict__ pn, const float* __restrict__ mn,
    const float* __restrict__ hid,
    f16* __restrict__ WIH1, f16* __restrict__ WLIN, f16* __restrict__ WP0,
    f16* __restrict__ XPAD, f16* __restrict__ Y0E, f16* __restrict__ Y1E,
    int* __restrict__ CNT)
{
  int i = blockIdx.x * 256 + threadIdx.x;            // 0..1121279
  if (i < 786432) { WIH1[i] = (f16)Wih1[i]; return; }
  i -= 786432;
  if (i < 262144) { WLIN[i] = (f16)Wlin[i]; return; }
  i -= 262144;
  if (i < 6144) {                                     // WP0 frags: f = jg*3+g
    int lane = i & 63; int f = i >> 6;
    int g = f % 3; int jg = f / 3;
    int kg = lane >> 4;
    int row = g * 512 + jg * 16 + (lane & 15);
    f16* dst = WP0 + (size_t)i * 8;
#pragma unroll
    for (int c = 0; c < 8; ++c)
      dst[c] = (kg == 0 && c < 6) ? (f16)Wih0[row * 6 + c] : (f16)0.f;
    return;
  }
  i -= 6144;
  if (i < 32768) {                                    // XPAD chunks
    size_t tb = i;
    f16* dst = XPAD + tb * 8;
#pragma unroll
    for (int c = 0; c < 8; ++c) {
      float v = (c < 4) ? pn[tb * 4 + c] : ((c < 6) ? mn[tb * 2 + (c - 4)] : 0.f);
      dst[c] = (f16)v;
    }
    return;
  }
  i -= 32768;
  if (i < 32768) {                                    // h0 slot0 of Y0E/Y1E
    int layer = i >> 14; int c = i & 16383;
    f16* dst = (layer ? Y1E : Y0E) + (size_t)c * 8;
    const float* src = hid + (size_t)layer * 131072 + (size_t)c * 8;
#pragma unroll
    for (int e = 0; e < 8; ++e) dst[e] = (f16)src[e];
    return;
  }
  i -= 32768;
  if (i < 1024) CNT[i] = 0;                           // both layers' counters
}

// ---------------- GRU layer: 64 WGs (4 batch-groups x 16 col-groups), weights in VGPRs ----
// WG: batch rows [WGb*64, +64), j-cols [WGj*32, +32). Wave = (batch-16) x (j-16) x 3 gates.
// h exchanged via yext[129][256][512]; per-step flag sync among the 16 col-WGs of a group.
template<int LAYER>
__global__ __launch_bounds__(512, 1) void gru3_k(
    const f16* __restrict__ PW, const f16* __restrict__ WP0,
    const f16* __restrict__ xpad, const f16* __restrict__ gip,
    const float* __restrict__ hidden_in,
    const float* __restrict__ b_ih, const float* __restrict__ b_hh,
    f16* __restrict__ yext, float* __restrict__ hT_out, int* __restrict__ cnt)
{
  __shared__ __align__(16) f16 hS[32768];   // [64 rows][512], swizzle: byte^=((row&7)<<4)
  const int tid = threadIdx.x, lane = tid & 63, wid = tid >> 6;
  const int colL = lane & 15, kgrp = lane >> 4;
  const int WGb = blockIdx.x & 3, WGj = blockIdx.x >> 2;
  const int bgl = wid & 3, jgl = wid >> 2;
  const int bgG = WGb * 4 + bgl;            // global batch-16 group 0..15
  const int jgG = WGj * 2 + jgl;            // global j-16 group 0..31
  const int bBase = WGb * 64;
  const int j = jgG * 16 + colL;

  float bs_r, bs_z, b_hn, b_in;
  if constexpr (LAYER == 0) {
    bs_r = b_ih[j] + b_hh[j];
    bs_z = b_ih[512 + j] + b_hh[512 + j];
    b_in = b_ih[1024 + j];
  } else {
    bs_r = b_hh[j]; bs_z = b_hh[512 + j]; b_in = 0.f;
  }
  b_hn = b_hh[1024 + j];

  float hreg[4];                            // fp32 h carry for this lane's (b,j) cells
#pragma unroll
  for (int i = 0; i < 4; ++i)
    hreg[i] = hidden_in[((size_t)LAYER * 256 + bgG * 16 + kgrp * 4 + i) * 512 + j];

  // ---- register-resident Whh slice: 48 frags = 192 VGPRs ----
  f16x8 Wr[48];
#pragma unroll
  for (int kt = 0; kt < 16; ++kt)
#pragma unroll
    for (int g = 0; g < 3; ++g)
      Wr[kt * 3 + g] = *(const f16x8*)(PW + (((size_t)(jgG * 16 + kt) * 3 + g) * 64 + lane) * 8);

  f16x8 WIr[3];
  if constexpr (LAYER == 0) {
#pragma unroll
    for (int g = 0; g < 3; ++g)
      WIr[g] = *(const f16x8*)(WP0 + (((size_t)jgG * 3 + g) * 64 + lane) * 8);
  }

  int* mycnt = cnt + WGb * 128;

  for (int t = 0; t < 128; ++t) {
    // ---- wait for h(t) from the 16 col-WGs of this batch group ----
    if (t > 0) {
      if (tid == 0) {
        int guard = 0;
        while (__hip_atomic_load(&mycnt[t - 1], __ATOMIC_RELAXED, __HIP_MEMORY_SCOPE_AGENT) < 16) {
          __builtin_amdgcn_s_sleep(4);
          if (++guard > (1 << 24)) break;
        }
      }
      __syncthreads();
      __threadfence();                      // acquire: no stale h(t) lines
    }
    // ---- stage h(t) rows [bBase,+64) into swizzled LDS ----
    {
      const f16* hsrc = yext + ((size_t)t * 256 + bBase) * 512;
#pragma unroll
      for (int s = 0; s < 8; ++s) {
        int cid = tid + 512 * s;
        int row = cid >> 6, ch = cid & 63;
        f16x8 v = *(const f16x8*)(hsrc + (size_t)row * 512 + ch * 8);
        *(f16x8*)((char*)hS + row * 1024 + ((ch * 16) ^ ((row & 7) << 4))) = v;
      }
    }
    __syncthreads();

    // ---- per-step inputs ----
    f16x4 giR, giZ, giN;
    f16x8 xA;
    if constexpr (LAYER == 1) {
      size_t fb = (((size_t)t * 16 + bgG) * 32 + jgG) * 3;
      giR = *(const f16x4*)(gip + (fb + 0) * 256 + lane * 4);
      giZ = *(const f16x4*)(gip + (fb + 1) * 256 + lane * 4);
      giN = *(const f16x4*)(gip + (fb + 2) * 256 + lane * 4);
    } else {
      xA = *(const f16x8*)(xpad + ((size_t)t * 256 + bBase + bgl * 16 + colL) * 8);
    }

    // ---- gh = h @ Whh^T for this wave's 3 gate tiles ----
    f32x4 ar, az, an_, ain;
#pragma unroll
    for (int q = 0; q < 4; ++q) { ar[q] = 0.f; az[q] = 0.f; an_[q] = 0.f; ain[q] = 0.f; }
#pragma unroll
    for (int kt = 0; kt < 16; ++kt) {
      f16x8 aF = *(const f16x8*)((char*)hS + (bgl * 16 + colL) * 1024 +
                                  ((kt * 64 + kgrp * 16) ^ ((colL & 7) << 4)));
      ar  = mfma16(aF, Wr[kt * 3 + 0], ar);
      az  = mfma16(aF, Wr[kt * 3 + 1], az);
      an_ = mfma16(aF, Wr[kt * 3 + 2], an_);
    }
    if constexpr (LAYER == 0) {
      ar  = mfma16(xA, WIr[0], ar);
      az  = mfma16(xA, WIr[1], az);
      ain = mfma16(xA, WIr[2], ain);
    }

    // ---- cell update; write h(t+1) slice (= y[t]) ----
#pragma unroll
    for (int i = 0; i < 4; ++i) {
      float rr, zz, hn, nin;
      if constexpr (LAYER == 0) {
        rr = ar[i] + bs_r; zz = az[i] + bs_z; hn = an_[i] + b_hn; nin = ain[i] + b_in;
      } else {
        rr = ar[i] + (float)giR[i] + bs_r;
        zz = az[i] + (float)giZ[i] + bs_z;
        hn = an_[i] + b_hn;
        nin = (float)giN[i];
      }
      float r = sigm(rr), z = sigm(zz);
      float n = tanh_fast(nin + r * hn);
      float hnew = (1.f - z) * n + z * hreg[i];
      hreg[i] = hnew;
      yext[((size_t)(t + 1) * 256 + bgG * 16 + kgrp * 4 + i) * 512 + j] = (f16)hnew;
    }

    // ---- release h(t+1): fence all threads' stores, then one flag inc ----
    __threadfence();
    __syncthreads();
    if (tid == 0)
      __hip_atomic_fetch_add(&mycnt[t], 1, __ATOMIC_RELEASE, __HIP_MEMORY_SCOPE_AGENT);
  }

#pragma unroll
  for (int i = 0; i < 4; ++i)
    hT_out[((size_t)bgG * 16 + kgrp * 4 + i) * 512 + j] = hreg[i];
}

// ---------------- gi1 = y0 @ Wih1^T + b_ih1, written in gru3 fragment layout ----------------
__global__ __launch_bounds__(256, 1) void gemm_gi1_k(
    const f16* __restrict__ A, const f16* __restrict__ B,
    const float* __restrict__ bias, f16* __restrict__ GIP)
{
  const int lane = threadIdx.x & 63, wd = threadIdx.x >> 6;
  const int colL = lane & 15, kgrp = lane >> 4;
  const int m0 = blockIdx.x * 64;
  const int n0 = blockIdx.y * 384 + wd * 96;
  f32x4 acc[4][6];
#pragma unroll
  for (int a = 0; a < 4; ++a)
#pragma unroll
    for (int n = 0; n < 6; ++n)
#pragma unroll
      for (int q = 0; q < 4; ++q) acc[a][n][q] = 0.f;

  for (int kt = 0; kt < 16; ++kt) {
    f16x8 aF[4];
#pragma unroll
    for (int at = 0; at < 4; ++at)
      aF[at] = *(const f16x8*)(A + ((size_t)(m0 + at * 16 + colL)) * 512 + kt * 32 + kgrp * 8);
#pragma unroll
    for (int nt = 0; nt < 6; ++nt) {
      f16x8 bF = *(const f16x8*)(B + ((size_t)(n0 + nt * 16 + colL)) * 512 + kt * 32 + kgrp * 8);
#pragma unroll
      for (int at = 0; at < 4; ++at)
        acc[at][nt] = mfma16(aF[at], bF, acc[at][nt]);
    }
  }

  const int t = m0 >> 8;
  const int bg0 = (m0 & 255) >> 4;
#pragma unroll
  for (int nt = 0; nt < 6; ++nt) {
    int colbase = n0 + nt * 16;
    int g = colbase >> 9;
    int jg = (colbase & 511) >> 4;
    float bv = bias[colbase + colL];
#pragma unroll
    for (int at = 0; at < 4; ++at) {
      size_t frag = (((size_t)t * 16 + bg0 + at) * 32 + jg) * 3 + g;
      f16x4 v = {(f16)(acc[at][nt][0] + bv), (f16)(acc[at][nt][1] + bv),
                 (f16)(acc[at][nt][2] + bv), (f16)(acc[at][nt][3] + bv)};
      *(f16x4*)(GIP + frag * 256 + lane * 4) = v;
    }
  }
}

// ---------------- u = y1 @ Wlin^T + b_lin (fp32 out) ----------------
__global__ __launch_bounds__(256, 1) void gemm_u_k(
    const f16* __restrict__ A, const f16* __restrict__ B,
    const float* __restrict__ bias, float* __restrict__ C)
{
  const int lane = threadIdx.x & 63, wd = threadIdx.x >> 6;
  const int colL = lane & 15, kgrp = lane >> 4;
  const int m0 = blockIdx.x * 64;
  const int n0 = wd * 128;
  f32x4 acc[4][8];
#pragma unroll
  for (int a = 0; a < 4; ++a)
#pragma unroll
    for (int n = 0; n < 8; ++n)
#pragma unroll
      for (int q = 0; q < 4; ++q) acc[a][n][q] = 0.f;

  for (int kt = 0; kt < 16; ++kt) {
    f16x8 aF[4];
#pragma unroll
    for (int at = 0; at < 4; ++at)
      aF[at] = *(const f16x8*)(A + ((size_t)(m0 + at * 16 + colL)) * 512 + kt * 32 + kgrp * 8);
#pragma unroll
    for (int nt = 0; nt < 8; ++nt) {
      f16x8 bF = *(const f16x8*)(B + ((size_t)(n0 + nt * 16 + colL)) * 512 + kt * 32 + kgrp * 8);
#pragma unroll
      for (int at = 0; at < 4; ++at)
        acc[at][nt] = mfma16(aF[at], bF, acc[at][nt]);
    }
  }
#pragma unroll
  for (int nt = 0; nt < 8; ++nt) {
    int col = n0 + nt * 16 + colL;
    float bv = bias[col];
#pragma unroll
    for (int at = 0; at < 4; ++at)
#pragma unroll
      for (int i = 0; i < 4; ++i)
        C[((size_t)(m0 + at * 16 + kgrp * 4 + i)) * 512 + col] = acc[at][nt][i] + bv;
  }
}

// ---------------- normalization pass 1 ----------------
__global__ __launch_bounds__(256) void norm1_k(const float* __restrict__ U,
    float* __restrict__ dsuf, float* __restrict__ de, float* __restrict__ du)
{
  int id = blockIdx.x * 4 + (threadIdx.x >> 6);
  int lane = threadIdx.x & 63;
  int k = id >> 8;
  const float* row = U + (size_t)id * 512;
  f32x4 v0 = *(const f32x4*)(row + lane * 8);
  f32x4 v1 = *(const f32x4*)(row + lane * 8 + 4);
  float vals[8] = {v0[0], v0[1], v0[2], v0[3], v1[0], v1[1], v1[2], v1[3]};
  int j0 = lane * 8;
  float s = 0.f;
#pragma unroll
  for (int q = 0; q < 8; ++q) {
    float v = ((j0 + q) >= 4 * k) ? vals[q] : 0.f;
    s += v * v;
  }
#pragma unroll
  for (int off = 1; off < 64; off <<= 1) s += __shfl_xor(s, off);
  if (lane == (k >> 1)) {
    int o = (k & 1) * 4;
    float e = vals[o] * vals[o] + vals[o + 1] * vals[o + 1] +
              vals[o + 2] * vals[o + 2] + vals[o + 3] * vals[o + 3];
    de[id] = e; dsuf[id] = s;
    f32x4 d = {vals[o], vals[o + 1], vals[o + 2], vals[o + 3]};
    *(f32x4*)(du + (size_t)id * 4) = d;
  }
}

// ---------------- normalization pass 2 ----------------
__global__ __launch_bounds__(256) void norm2_k(const float* __restrict__ dsuf,
    const float* __restrict__ de, const float* __restrict__ du, float* __restrict__ out)
{
  int b = threadIdx.x;
  float L = 128.f;
  for (int kc = 0; kc < 8; ++kc) {
    float ss[16], ee[16]; f32x4 dd[16];
#pragma unroll
    for (int q = 0; q < 16; ++q) {
      int id = (kc * 16 + q) * 256 + b;
      ss[q] = dsuf[id]; ee[q] = de[id];
      dd[q] = *(const f32x4*)(du + (size_t)id * 4);
    }
#pragma unroll
    for (int q = 0; q < 16; ++q) {
      int id = (kc * 16 + q) * 256 + b;
      float sc = sqrtf(L / ss[q]);
      f32x4 o = dd[q];
      o[0] *= sc; o[1] *= sc; o[2] *= sc; o[3] *= sc;
      *(f32x4*)(out + (size_t)id * 4) = o;
      L *= (1.f - ee[q] / ss[q]);
    }
  }
}

// ---------------- launch ----------------
extern "C" void kernel_launch(void* const* d_in, const int* in_sizes, int n_in,
                              void* d_out, int out_size, void* d_ws, size_t ws_size,
                              hipStream_t stream) {
  (void)in_sizes; (void)n_in; (void)out_size; (void)ws_size;
  const float* pn   = (const float*)d_in[0];
  const float* mn   = (const float*)d_in[1];
  const float* hid  = (const float*)d_in[2];
  const float* Wih0 = (const float*)d_in[3];
  const float* Whh0 = (const float*)d_in[4];
  const float* bih0 = (const float*)d_in[5];
  const float* bhh0 = (const float*)d_in[6];
  const float* Wih1 = (const float*)d_in[7];
  const float* Whh1 = (const float*)d_in[8];
  const float* bih1 = (const float*)d_in[9];
  const float* bhh1 = (const float*)d_in[10];
  const float* Wlin = (const float*)d_in[11];
  const float* blin = (const float*)d_in[12];
  float* out = (float*)d_out;
  char* ws = (char*)d_ws;

  f16* PW0  = (f16*)(ws + OFF_PW0);
  f16* PW1  = (f16*)(ws + OFF_PW1);
  f16* WIH1 = (f16*)(ws + OFF_WIH1);
  f16* WLIN = (f16*)(ws + OFF_WLIN);
  f16* WP0  = (f16*)(ws + OFF_WP0);
  f16* XPAD = (f16*)(ws + OFF_XPAD);
  int* CNT  = (int*)(ws + OFF_CNT);
  f16* Y0E  = (f16*)(ws + OFF_Y0E);
  f16* Y1E  = (f16*)(ws + OFF_Y1E);
  f16* GIP  = (f16*)(ws + OFF_GIU);
  float* U  = (float*)(ws + OFF_GIU);
  float* DSUF = (float*)(ws + OFF_DIAG);
  float* DE   = (float*)(ws + OFF_DIAG + 131072);
  float* DU   = (float*)(ws + OFF_DIAG + 262144);

  prep_pack_k<<<768, 256, 0, stream>>>(Whh0, Whh1, PW0, PW1);
  prep_misc_k<<<4380, 256, 0, stream>>>(Wih1, Wlin, Wih0, pn, mn, hid,
                                        WIH1, WLIN, WP0, XPAD, Y0E, Y1E, CNT);
  gru3_k<0><<<64, 512, 0, stream>>>(PW0, WP0, XPAD, nullptr, hid, bih0, bhh0,
                                    Y0E, out + 131072, CNT);
  gemm_gi1_k<<<dim3(512, 4), 256, 0, stream>>>(Y0E + 131072, WIH1, bih1, GIP);
  gru3_k<1><<<64, 512, 0, stream>>>(PW1, nullptr, nullptr, GIP, hid, bih1, bhh1,
                                    Y1E, out + 262144, CNT + 512);
  gemm_u_k<<<512, 256, 0, stream>>>(Y1E + 131072, WLIN, blin, U);
  norm1_k<<<8192, 256, 0, stream>>>(U, DSUF, DE, DU);
  norm2_k<<<1, 256, 0, stream>>>(DSUF, DE, DU, out);
}

// Round 5
// 1119.331 us; speedup vs baseline: 6.1043x; 6.1043x over previous
//
#include <hip/hip_runtime.h>

typedef _Float16 f16;
typedef _Float16 f16x8 __attribute__((ext_vector_type(8)));
typedef _Float16 f16x4 __attribute__((ext_vector_type(4)));
typedef float f32x4 __attribute__((ext_vector_type(4)));

__device__ __forceinline__ f32x4 mfma16(f16x8 a, f16x8 b, f32x4 c) {
  return __builtin_amdgcn_mfma_f32_16x16x32_f16(a, b, c, 0, 0, 0);
}
__device__ __forceinline__ float sigm(float x) { return 1.0f / (1.0f + __expf(-x)); }
__device__ __forceinline__ float tanh_fast(float x) { return 1.0f - 2.0f / (__expf(2.0f * x) + 1.0f); }

// device-scope (coherence-point) memory ops: bypass the non-coherent L1/L2 path
__device__ __forceinline__ f16x8 load_b128_dev(const void* addr) {
  f16x8 r;
  asm volatile("global_load_dwordx4 %0, %1, off sc0 sc1" : "=v"(r) : "v"(addr) : "memory");
  return r;  // caller MUST s_waitcnt vmcnt(0) before use
}
__device__ __forceinline__ void store_f16_dev(void* addr, f16 v) {
  int iv = (int)__builtin_bit_cast(unsigned short, v);
  asm volatile("global_store_short %0, %1, off sc0 sc1" :: "v"(addr), "v"(iv) : "memory");
}

// ---------------- workspace layout (bytes) ----------------
constexpr size_t OFF_PW0   = 0;                        // packed Whh L0 frags, 1.5MB
constexpr size_t OFF_PW1   = 1572864;                  // packed Whh L1 frags, 1.5MB
constexpr size_t OFF_WIH1  = 3145728;                  // plain f16 [1536][512], 1.5MB
constexpr size_t OFF_WLIN  = 4718592;                  // plain f16 [512][512], 0.5MB
constexpr size_t OFF_WP0   = 5242880;                  // layer0 Wih frags [96][64][8], 96KB
constexpr size_t OFF_XPAD  = 5341184;                  // [128][256][8] f16, 512KB
constexpr size_t OFF_CNT   = 5865472;                  // 2 layers x 8 groups x 128 ints, 8KB
constexpr size_t OFF_Y0E   = 5873664;                  // [129][256][512] f16, 33.8MB (slot0=h0)
constexpr size_t OFF_Y1E   = 39690240;                 // [129][256][512] f16, 33.8MB
constexpr size_t OFF_GIU   = 73506816;                 // GIP f16 100.7MB, then U f32 64MB aliased
constexpr size_t OFF_DIAG  = 174170112;                // dsuf/de/du

// ---------------- prep: pack Whh into fragment order ----------------
// frag f = jg*48 + kt*3 + g  (jg 0..31, kt 0..15, g 0..2); [f][lane(64)][8 f16]
// content: row = g*512 + jg*16 + (lane&15); k = kt*32 + (lane>>4)*8
__global__ __launch_bounds__(256) void prep_pack_k(
    const float* __restrict__ Whh0, const float* __restrict__ Whh1,
    f16* __restrict__ P0, f16* __restrict__ P1)
{
  int idx = blockIdx.x * 256 + threadIdx.x;          // 0..196607
  const float* W = (idx < 98304) ? Whh0 : Whh1;
  f16* P = (idx < 98304) ? P0 : P1;
  int q = (idx < 98304) ? idx : idx - 98304;         // (98304 not pow2: subtract!)
  int lane = q & 63; int f = q >> 6;                 // f 0..1535
  int g = f % 3; int u = f / 3;                      // u 0..511
  int kt = u & 15; int jg = u >> 4;                  // jg 0..31
  int row = g * 512 + jg * 16 + (lane & 15);
  int k = kt * 32 + (lane >> 4) * 8;
  const float* src = W + (size_t)row * 512 + k;
  f16* dst = P + (size_t)q * 8;
#pragma unroll
  for (int c = 0; c < 8; ++c) dst[c] = (f16)src[c];
}

// ---------------- prep: weights, x packing, h0 slots, counter zeroing ----------------
__global__ __launch_bounds__(256) void prep_misc_k(
    const float* __restrict__ Wih1, const float* __restrict__ Wlin,
    const float* __restrict__ Wih0, const float* __restrict__ pn, const float* __restrict__ mn,
    const float* __restrict__ hid,
    f16* __restrict__ WIH1, f16* __restrict__ WLIN, f16* __restrict__ WP0,
    f16* __restrict__ XPAD, f16* __restrict__ Y0E, f16* __restrict__ Y1E,
    int* __restrict__ CNT)
{
  int i = blockIdx.x * 256 + threadIdx.x;            // 0..1122303
  if (i < 786432) { WIH1[i] = (f16)Wih1[i]; return; }
  i -= 786432;
  if (i < 262144) { WLIN[i] = (f16)Wlin[i]; return; }
  i -= 262144;
  if (i < 6144) {                                     // WP0 frags: f = jg*3+g
    int lane = i & 63; int f = i >> 6;
    int g = f % 3; int jg = f / 3;
    int kg = lane >> 4;
    int row = g * 512 + jg * 16 + (lane & 15);
    f16* dst = WP0 + (size_t)i * 8;
#pragma unroll
    for (int c = 0; c < 8; ++c)
      dst[c] = (kg == 0 && c < 6) ? (f16)Wih0[row * 6 + c] : (f16)0.f;
    return;
  }
  i -= 6144;
  if (i < 32768) {                                    // XPAD chunks
    size_t tb = i;
    f16* dst = XPAD + tb * 8;
#pragma unroll
    for (int c = 0; c < 8; ++c) {
      float v = (c < 4) ? pn[tb * 4 + c] : ((c < 6) ? mn[tb * 2 + (c - 4)] : 0.f);
      dst[c] = (f16)v;
    }
    return;
  }
  i -= 32768;
  if (i < 32768) {                                    // h0 slot0 of Y0E/Y1E
    int layer = i >> 14; int c = i & 16383;
    f16* dst = (layer ? Y1E : Y0E) + (size_t)c * 8;
    const float* src = hid + (size_t)layer * 131072 + (size_t)c * 8;
#pragma unroll
    for (int e = 0; e < 8; ++e) dst[e] = (f16)src[e];
    return;
  }
  i -= 32768;
  if (i < 2048) CNT[i] = 0;
}

// ---------------- GRU layer: 128 WGs (8 batch-groups x 16 col-WGs) ----------------
// WG: batch rows [WGb*32,+32), j-cols [WGj*32,+32); 256 thr = 4 waves (2 bgl x 2 jgl).
// Weights slice LDS-resident (96KB); h tile staged in LDS (32KB, XOR-swizzled).
// h exchange via yext[t] fresh slots with device-scope (sc0 sc1) ops; flag per (group,t).
template<int LAYER>
__global__ __launch_bounds__(256, 1) void gru4_k(
    const f16* __restrict__ PW, const f16* __restrict__ WP0,
    const f16* __restrict__ xpad, const f16* __restrict__ gip,
    const float* __restrict__ hidden_in,
    const float* __restrict__ b_ih, const float* __restrict__ b_hh,
    f16* __restrict__ yext, float* __restrict__ hT_out, int* __restrict__ cnt)
{
  extern __shared__ char smem[];             // [0,32KB) hS swizzled, [32KB,128KB) weights
  char* hSb = smem;
  char* WLb = smem + 32768;
  const int tid = threadIdx.x, lane = tid & 63, wid = tid >> 6;
  const int colL = lane & 15, kgrp = lane >> 4;
  const int WGb = blockIdx.x & 7, WGj = blockIdx.x >> 3;
  const int bgl = wid & 1, jgl = wid >> 1;
  const int bgG = WGb * 2 + bgl;             // global batch-16 group 0..15
  const int jgG = WGj * 2 + jgl;             // global j-16 group 0..31
  const int bBase = WGb * 32;
  const int j = jgG * 16 + colL;

  // ---- load this WG's 96KB weight slice into LDS (frags [WGj*96, +96) contiguous) ----
  {
    const f16* wsrc = PW + (size_t)WGj * 96 * 512;
#pragma unroll
    for (int c = 0; c < 24; ++c) {
      int cid = tid + 256 * c;
      *(f16x8*)(WLb + (size_t)cid * 16) = *(const f16x8*)(wsrc + (size_t)cid * 8);
    }
  }

  float bs_r, bs_z, b_hn, b_in;
  if constexpr (LAYER == 0) {
    bs_r = b_ih[j] + b_hh[j];
    bs_z = b_ih[512 + j] + b_hh[512 + j];
    b_in = b_ih[1024 + j];
  } else {
    bs_r = b_hh[j]; bs_z = b_hh[512 + j]; b_in = 0.f;
  }
  b_hn = b_hh[1024 + j];

  float hreg[4];
#pragma unroll
  for (int i = 0; i < 4; ++i)
    hreg[i] = hidden_in[((size_t)LAYER * 256 + bgG * 16 + kgrp * 4 + i) * 512 + j];

  f16x8 WIr[3];
  f16x8 xA;
  f16x4 giR, giZ, giN;
  if constexpr (LAYER == 0) {
#pragma unroll
    for (int g = 0; g < 3; ++g)
      WIr[g] = *(const f16x8*)(WP0 + (((size_t)jgG * 3 + g) * 64 + lane) * 8);
    xA = *(const f16x8*)(xpad + ((size_t)bgG * 16 + colL) * 8);
  } else {
    size_t fb = ((size_t)bgG * 32 + jgG) * 3;
    giR = *(const f16x4*)(gip + (fb + 0) * 256 + lane * 4);
    giZ = *(const f16x4*)(gip + (fb + 1) * 256 + lane * 4);
    giN = *(const f16x4*)(gip + (fb + 2) * 256 + lane * 4);
  }

  int* mycnt = cnt + WGb * 128;

  for (int t = 0; t < 128; ++t) {
    // ---- acquire h(t): wait for the 16 col-WGs of this batch group ----
    if (t > 0) {
      if (tid == 0) {
        int guard = 0;
        while (__hip_atomic_load(&mycnt[t - 1], __ATOMIC_RELAXED, __HIP_MEMORY_SCOPE_AGENT) < 16) {
          __builtin_amdgcn_s_sleep(2);
          if (++guard > (1 << 20)) break;
        }
      }
      __syncthreads();
    }

    // ---- stage h(t) rows [bBase,+32) into swizzled LDS via device-scope loads ----
    {
      const char* base = (const char*)yext + ((size_t)t * 256 + bBase) * 1024;
      f16x8 tmp[8];
#pragma unroll
      for (int s = 0; s < 8; ++s) {
        int cid = tid + 256 * s;               // row = cid>>6 (0..31), ch = cid&63
        tmp[s] = load_b128_dev(base + (size_t)(cid >> 6) * 1024 + (cid & 63) * 16);
      }
      asm volatile("s_waitcnt vmcnt(0)" ::: "memory");
      __builtin_amdgcn_sched_barrier(0);
#pragma unroll
      for (int s = 0; s < 8; ++s) {
        int cid = tid + 256 * s;
        int row = cid >> 6, ch = cid & 63;
        *(f16x8*)(hSb + row * 1024 + ((ch * 16) ^ ((row & 7) << 4))) = tmp[s];
      }
    }
    __syncthreads();   // hS ready (also covers WL copy on t==0)

    // ---- gh = h @ Whh^T (3 gate tiles), weights from LDS ----
    f32x4 ar, az, an_, ain;
#pragma unroll
    for (int q = 0; q < 4; ++q) { ar[q] = 0.f; az[q] = 0.f; an_[q] = 0.f; ain[q] = 0.f; }
#pragma unroll
    for (int kt = 0; kt < 16; ++kt) {
      f16x8 aF = *(const f16x8*)(hSb + (bgl * 16 + colL) * 1024 +
                                  ((kt * 64 + kgrp * 16) ^ ((colL & 7) << 4)));
      const char* wb = WLb + (size_t)(jgl * 48 + kt * 3) * 1024 + lane * 16;
      ar  = mfma16(aF, *(const f16x8*)(wb),        ar);
      az  = mfma16(aF, *(const f16x8*)(wb + 1024), az);
      an_ = mfma16(aF, *(const f16x8*)(wb + 2048), an_);
    }
    if constexpr (LAYER == 0) {
      ar  = mfma16(xA, WIr[0], ar);
      az  = mfma16(xA, WIr[1], az);
      ain = mfma16(xA, WIr[2], ain);
    }

    // ---- cell update; device-scope store of h(t+1) slice (= y[t]) ----
    {
      f16* yb = yext + ((size_t)(t + 1) * 256 + bgG * 16 + kgrp * 4) * 512 + j;
#pragma unroll
      for (int i = 0; i < 4; ++i) {
        float rr, zz, hn, nin;
        if constexpr (LAYER == 0) {
          rr = ar[i] + bs_r; zz = az[i] + bs_z; hn = an_[i] + b_hn; nin = ain[i] + b_in;
        } else {
          rr = ar[i] + (float)giR[i] + bs_r;
          zz = az[i] + (float)giZ[i] + bs_z;
          hn = an_[i] + b_hn;
          nin = (float)giN[i];
        }
        float r = sigm(rr), z = sigm(zz);
        float n = tanh_fast(nin + r * hn);
        float hnew = (1.f - z) * n + z * hreg[i];
        hreg[i] = hnew;
        store_f16_dev(yb + (size_t)i * 512, (f16)hnew);
      }
    }

    // ---- release: drain stores to coherence point, then bump flag ----
    asm volatile("s_waitcnt vmcnt(0)" ::: "memory");
    __syncthreads();
    if (tid == 0)
      __hip_atomic_fetch_add(&mycnt[t], 1, __ATOMIC_RELAXED, __HIP_MEMORY_SCOPE_AGENT);

    // ---- prefetch next step's x / gi (overlaps the next acquire spin) ----
    {
      int tn = (t + 1) & 127;
      if constexpr (LAYER == 0) {
        xA = *(const f16x8*)(xpad + ((size_t)tn * 256 + bgG * 16 + colL) * 8);
      } else {
        size_t fb = (((size_t)tn * 16 + bgG) * 32 + jgG) * 3;
        giR = *(const f16x4*)(gip + (fb + 0) * 256 + lane * 4);
        giZ = *(const f16x4*)(gip + (fb + 1) * 256 + lane * 4);
        giN = *(const f16x4*)(gip + (fb + 2) * 256 + lane * 4);
      }
    }
  }

#pragma unroll
  for (int i = 0; i < 4; ++i)
    hT_out[((size_t)bgG * 16 + kgrp * 4 + i) * 512 + j] = hreg[i];
}

// ---------------- gi1 = y0 @ Wih1^T + b_ih1, written in gru4 fragment layout ----------------
__global__ __launch_bounds__(256, 1) void gemm_gi1_k(
    const f16* __restrict__ A, const f16* __restrict__ B,
    const float* __restrict__ bias, f16* __restrict__ GIP)
{
  const int lane = threadIdx.x & 63, wd = threadIdx.x >> 6;
  const int colL = lane & 15, kgrp = lane >> 4;
  const int m0 = blockIdx.x * 64;
  const int n0 = blockIdx.y * 384 + wd * 96;
  f32x4 acc[4][6];
#pragma unroll
  for (int a = 0; a < 4; ++a)
#pragma unroll
    for (int n = 0; n < 6; ++n)
#pragma unroll
      for (int q = 0; q < 4; ++q) acc[a][n][q] = 0.f;

  for (int kt = 0; kt < 16; ++kt) {
    f16x8 aF[4];
#pragma unroll
    for (int at = 0; at < 4; ++at)
      aF[at] = *(const f16x8*)(A + ((size_t)(m0 + at * 16 + colL)) * 512 + kt * 32 + kgrp * 8);
#pragma unroll
    for (int nt = 0; nt < 6; ++nt) {
      f16x8 bF = *(const f16x8*)(B + ((size_t)(n0 + nt * 16 + colL)) * 512 + kt * 32 + kgrp * 8);
#pragma unroll
      for (int at = 0; at < 4; ++at)
        acc[at][nt] = mfma16(aF[at], bF, acc[at][nt]);
    }
  }

  const int t = m0 >> 8;
  const int bg0 = (m0 & 255) >> 4;
#pragma unroll
  for (int nt = 0; nt < 6; ++nt) {
    int colbase = n0 + nt * 16;
    int g = colbase >> 9;
    int jg = (colbase & 511) >> 4;
    float bv = bias[colbase + colL];
#pragma unroll
    for (int at = 0; at < 4; ++at) {
      size_t frag = (((size_t)t * 16 + bg0 + at) * 32 + jg) * 3 + g;
      f16x4 v = {(f16)(acc[at][nt][0] + bv), (f16)(acc[at][nt][1] + bv),
                 (f16)(acc[at][nt][2] + bv), (f16)(acc[at][nt][3] + bv)};
      *(f16x4*)(GIP + frag * 256 + lane * 4) = v;
    }
  }
}

// ---------------- u = y1 @ Wlin^T + b_lin (fp32 out) ----------------
__global__ __launch_bounds__(256, 1) void gemm_u_k(
    const f16* __restrict__ A, const f16* __restrict__ B,
    const float* __restrict__ bias, float* __restrict__ C)
{
  const int lane = threadIdx.x & 63, wd = threadIdx.x >> 6;
  const int colL = lane & 15, kgrp = lane >> 4;
  const int m0 = blockIdx.x * 64;
  const int n0 = wd * 128;
  f32x4 acc[4][8];
#pragma unroll
  for (int a = 0; a < 4; ++a)
#pragma unroll
    for (int n = 0; n < 8; ++n)
#pragma unroll
      for (int q = 0; q < 4; ++q) acc[a][n][q] = 0.f;

  for (int kt = 0; kt < 16; ++kt) {
    f16x8 aF[4];
#pragma unroll
    for (int at = 0; at < 4; ++at)
      aF[at] = *(const f16x8*)(A + ((size_t)(m0 + at * 16 + colL)) * 512 + kt * 32 + kgrp * 8);
#pragma unroll
    for (int nt = 0; nt < 8; ++nt) {
      f16x8 bF = *(const f16x8*)(B + ((size_t)(n0 + nt * 16 + colL)) * 512 + kt * 32 + kgrp * 8);
#pragma unroll
      for (int at = 0; at < 4; ++at)
        acc[at][nt] = mfma16(aF[at], bF, acc[at][nt]);
    }
  }
#pragma unroll
  for (int nt = 0; nt < 8; ++nt) {
    int col = n0 + nt * 16 + colL;
    float bv = bias[col];
#pragma unroll
    for (int at = 0; at < 4; ++at)
#pragma unroll
      for (int i = 0; i < 4; ++i)
        C[((size_t)(m0 + at * 16 + kgrp * 4 + i)) * 512 + col] = acc[at][nt][i] + bv;
  }
}

// ---------------- normalization pass 1 ----------------
__global__ __launch_bounds__(256) void norm1_k(const float* __restrict__ U,
    float* __restrict__ dsuf, float* __restrict__ de, float* __restrict__ du)
{
  int id = blockIdx.x * 4 + (threadIdx.x >> 6);
  int lane = threadIdx.x & 63;
  int k = id >> 8;
  const float* row = U + (size_t)id * 512;
  f32x4 v0 = *(const f32x4*)(row + lane * 8);
  f32x4 v1 = *(const f32x4*)(row + lane * 8 + 4);
  float vals[8] = {v0[0], v0[1], v0[2], v0[3], v1[0], v1[1], v1[2], v1[3]};
  int j0 = lane * 8;
  float s = 0.f;
#pragma unroll
  for (int q = 0; q < 8; ++q) {
    float v = ((j0 + q) >= 4 * k) ? vals[q] : 0.f;
    s += v * v;
  }
#pragma unroll
  for (int off = 1; off < 64; off <<= 1) s += __shfl_xor(s, off);
  if (lane == (k >> 1)) {
    int o = (k & 1) * 4;
    float e = vals[o] * vals[o] + vals[o + 1] * vals[o + 1] +
              vals[o + 2] * vals[o + 2] + vals[o + 3] * vals[o + 3];
    de[id] = e; dsuf[id] = s;
    f32x4 d = {vals[o], vals[o + 1], vals[o + 2], vals[o + 3]};
    *(f32x4*)(du + (size_t)id * 4) = d;
  }
}

// ---------------- normalization pass 2 ----------------
__global__ __launch_bounds__(256) void norm2_k(const float* __restrict__ dsuf,
    const float* __restrict__ de, const float* __restrict__ du, float* __restrict__ out)
{
  int b = threadIdx.x;
  float L = 128.f;
  for (int kc = 0; kc < 8; ++kc) {
    float ss[16], ee[16]; f32x4 dd[16];
#pragma unroll
    for (int q = 0; q < 16; ++q) {
      int id = (kc * 16 + q) * 256 + b;
      ss[q] = dsuf[id]; ee[q] = de[id];
      dd[q] = *(const f32x4*)(du + (size_t)id * 4);
    }
#pragma unroll
    for (int q = 0; q < 16; ++q) {
      int id = (kc * 16 + q) * 256 + b;
      float sc = sqrtf(L / ss[q]);
      f32x4 o = dd[q];
      o[0] *= sc; o[1] *= sc; o[2] *= sc; o[3] *= sc;
      *(f32x4*)(out + (size_t)id * 4) = o;
      L *= (1.f - ee[q] / ss[q]);
    }
  }
}

// ---------------- launch ----------------
extern "C" void kernel_launch(void* const* d_in, const int* in_sizes, int n_in,
                              void* d_out, int out_size, void* d_ws, size_t ws_size,
                              hipStream_t stream) {
  (void)in_sizes; (void)n_in; (void)out_size; (void)ws_size;
  const float* pn   = (const float*)d_in[0];
  const float* mn   = (const float*)d_in[1];
  const float* hid  = (const float*)d_in[2];
  const float* Wih0 = (const float*)d_in[3];
  const float* Whh0 = (const float*)d_in[4];
  const float* bih0 = (const float*)d_in[5];
  const float* bhh0 = (const float*)d_in[6];
  const float* Wih1 = (const float*)d_in[7];
  const float* Whh1 = (const float*)d_in[8];
  const float* bih1 = (const float*)d_in[9];
  const float* bhh1 = (const float*)d_in[10];
  const float* Wlin = (const float*)d_in[11];
  const float* blin = (const float*)d_in[12];
  float* out = (float*)d_out;
  char* ws = (char*)d_ws;

  f16* PW0  = (f16*)(ws + OFF_PW0);
  f16* PW1  = (f16*)(ws + OFF_PW1);
  f16* WIH1 = (f16*)(ws + OFF_WIH1);
  f16* WLIN = (f16*)(ws + OFF_WLIN);
  f16* WP0  = (f16*)(ws + OFF_WP0);
  f16* XPAD = (f16*)(ws + OFF_XPAD);
  int* CNT  = (int*)(ws + OFF_CNT);
  f16* Y0E  = (f16*)(ws + OFF_Y0E);
  f16* Y1E  = (f16*)(ws + OFF_Y1E);
  f16* GIP  = (f16*)(ws + OFF_GIU);
  float* U  = (float*)(ws + OFF_GIU);
  float* DSUF = (float*)(ws + OFF_DIAG);
  float* DE   = (float*)(ws + OFF_DIAG + 131072);
  float* DU   = (float*)(ws + OFF_DIAG + 262144);

  hipFuncSetAttribute(reinterpret_cast<const void*>(gru4_k<0>),
                      hipFuncAttributeMaxDynamicSharedMemorySize, 131072);
  hipFuncSetAttribute(reinterpret_cast<const void*>(gru4_k<1>),
                      hipFuncAttributeMaxDynamicSharedMemorySize, 131072);

  prep_pack_k<<<768, 256, 0, stream>>>(Whh0, Whh1, PW0, PW1);
  prep_misc_k<<<4384, 256, 0, stream>>>(Wih1, Wlin, Wih0, pn, mn, hid,
                                        WIH1, WLIN, WP0, XPAD, Y0E, Y1E, CNT);
  gru4_k<0><<<128, 256, 131072, stream>>>(PW0, WP0, XPAD, nullptr, hid, bih0, bhh0,
                                          Y0E, out + 131072, CNT);
  gemm_gi1_k<<<dim3(512, 4), 256, 0, stream>>>(Y0E + 131072, WIH1, bih1, GIP);
  gru4_k<1><<<128, 256, 131072, stream>>>(PW1, nullptr, nullptr, GIP, hid, bih1, bhh1,
                                          Y1E, out + 262144, CNT + 1024);
  gemm_u_k<<<512, 256, 0, stream>>>(Y1E + 131072, WLIN, blin, U);
  norm1_k<<<8192, 256, 0, stream>>>(U, DSUF, DE, DU);
  norm2_k<<<1, 256, 0, stream>>>(DSUF, DE, DU, out);
}

// Round 6
// 817.592 us; speedup vs baseline: 8.3571x; 1.3691x over previous
//
#include <hip/hip_runtime.h>

typedef _Float16 f16;
typedef _Float16 f16x8 __attribute__((ext_vector_type(8)));
typedef float f32x4 __attribute__((ext_vector_type(4)));

__device__ __forceinline__ f32x4 mfma16(f16x8 a, f16x8 b, f32x4 c) {
  return __builtin_amdgcn_mfma_f32_16x16x32_f16(a, b, c, 0, 0, 0);
}
__device__ __forceinline__ float sigm(float x) { return 1.0f / (1.0f + __expf(-x)); }
__device__ __forceinline__ float tanh_fast(float x) { return 1.0f - 2.0f / (__expf(2.0f * x) + 1.0f); }

// device-scope (coherence-point) memory ops: bypass the non-coherent per-XCD L2 path
__device__ __forceinline__ f16x8 load_b128_dev(const void* addr) {
  f16x8 r;
  asm volatile("global_load_dwordx4 %0, %1, off sc0 sc1" : "=v"(r) : "v"(addr) : "memory");
  return r;  // caller MUST s_waitcnt vmcnt(0) before use
}
__device__ __forceinline__ void store_f16_dev(void* addr, f16 v) {
  int iv = (int)__builtin_bit_cast(unsigned short, v);
  asm volatile("global_store_short %0, %1, off sc0 sc1" :: "v"(addr), "v"(iv) : "memory");
}

// ---------------- workspace layout (bytes) ----------------
constexpr size_t OFF_PW0   = 0;            // packed Whh0 frags, 1.5MB
constexpr size_t OFF_PW1   = 1572864;      // packed Whh1 frags, 1.5MB
constexpr size_t OFF_PWI1  = 3145728;      // packed Wih1 frags, 1.5MB
constexpr size_t OFF_WLIN  = 4718592;      // plain f16 [512][512], 0.5MB
constexpr size_t OFF_WP0   = 5242880;      // layer0 Wih frags [96][64][8], 96KB
constexpr size_t OFF_XPAD  = 5341184;      // [128][256][8] f16, 512KB
constexpr size_t OFF_CNT   = 5865472;      // flag0[8][128] + flag1[8][128], 8KB
constexpr size_t OFF_Y0E   = 5873664;      // [129][256][512] f16, 33.8MB (slot0=h0)
constexpr size_t OFF_Y1E   = 39690240;     // [129][256][512] f16, 33.8MB
constexpr size_t OFF_U     = 73506816;     // U f32, 64MB
constexpr size_t OFF_DIAG  = 140615680;    // dsuf/de/du

// ---------------- prep: pack Whh0/Whh1/Wih1 into fragment order ----------------
// frag f = jg*48 + kt*3 + g; [f][lane(64)][8 f16]
// content: row = g*512 + jg*16 + (lane&15); k = kt*32 + (lane>>4)*8
__global__ __launch_bounds__(256) void prep_pack_k(
    const float* __restrict__ Whh0, const float* __restrict__ Whh1,
    const float* __restrict__ Wih1,
    f16* __restrict__ P0, f16* __restrict__ P1, f16* __restrict__ PI1)
{
  int idx = blockIdx.x * 256 + threadIdx.x;          // 0..294911
  int m = idx / 98304;                                // 98304 = 3*2^15: divide, don't mask
  int q = idx - m * 98304;
  const float* W = (m == 0) ? Whh0 : ((m == 1) ? Whh1 : Wih1);
  f16* P = (m == 0) ? P0 : ((m == 1) ? P1 : PI1);
  int lane = q & 63; int f = q >> 6;                 // f 0..1535
  int g = f % 3; int u = f / 3;
  int kt = u & 15; int jg = u >> 4;
  int row = g * 512 + jg * 16 + (lane & 15);
  int k = kt * 32 + (lane >> 4) * 8;
  const float* src = W + (size_t)row * 512 + k;
  f16* dst = P + (size_t)q * 8;
#pragma unroll
  for (int c = 0; c < 8; ++c) dst[c] = (f16)src[c];
}

// ---------------- prep: Wlin, layer0 input-weights, x packing, h0 slots, counters ----------------
__global__ __launch_bounds__(256) void prep_misc_k(
    const float* __restrict__ Wlin, const float* __restrict__ Wih0,
    const float* __restrict__ pn, const float* __restrict__ mn,
    const float* __restrict__ hid,
    f16* __restrict__ WLIN, f16* __restrict__ WP0, f16* __restrict__ XPAD,
    f16* __restrict__ Y0E, f16* __restrict__ Y1E, int* __restrict__ CNT)
{
  int i = blockIdx.x * 256 + threadIdx.x;            // 0..335871
  if (i < 262144) { WLIN[i] = (f16)Wlin[i]; return; }
  i -= 262144;
  if (i < 6144) {                                     // WP0 frags: f = jg*3+g
    int lane = i & 63; int f = i >> 6;
    int g = f % 3; int jg = f / 3;
    int kg = lane >> 4;
    int row = g * 512 + jg * 16 + (lane & 15);
    f16* dst = WP0 + (size_t)i * 8;
#pragma unroll
    for (int c = 0; c < 8; ++c)
      dst[c] = (kg == 0 && c < 6) ? (f16)Wih0[row * 6 + c] : (f16)0.f;
    return;
  }
  i -= 6144;
  if (i < 32768) {                                    // XPAD chunks
    size_t tb = i;
    f16* dst = XPAD + tb * 8;
#pragma unroll
    for (int c = 0; c < 8; ++c) {
      float v = (c < 4) ? pn[tb * 4 + c] : ((c < 6) ? mn[tb * 2 + (c - 4)] : 0.f);
      dst[c] = (f16)v;
    }
    return;
  }
  i -= 32768;
  if (i < 32768) {                                    // h0 slot0 of Y0E/Y1E
    int layer = i >> 14; int c = i & 16383;
    f16* dst = (layer ? Y1E : Y0E) + (size_t)c * 8;
    const float* src = hid + (size_t)layer * 131072 + (size_t)c * 8;
#pragma unroll
    for (int e = 0; e < 8; ++e) dst[e] = (f16)src[e];
    return;
  }
  i -= 32768;
  if (i < 2048) CNT[i] = 0;
}

__device__ __forceinline__ void spin_ge16(int* p) {
  int guard = 0;
  while (__hip_atomic_load(p, __ATOMIC_RELAXED, __HIP_MEMORY_SCOPE_AGENT) < 16) {
    __builtin_amdgcn_s_sleep(2);
    if (++guard > (1 << 20)) break;  // deadlock escape (never hit when co-resident)
  }
}

// ---------------- fused 2-layer GRU pipeline: 256 WGs, 1 WG/CU ----------------
// WGs [0,128): layer 0.  WGs [128,256): layer 1, running one step behind layer 0.
// Per layer: 8 batch-groups x 16 col-WGs; WG = (batch-32 x j-32), 4 waves (2x2).
// LDS: [0,96KB) Whh slice frags; [96KB,128KB) hS tile; [128KB,160KB) xS tile (L1).
// L1 computes gi(t) = y0(t) @ Wih1^T on the fly; Wih1 slice lives in 192 VGPRs.
__global__ __launch_bounds__(256, 1) void gru_fused_k(
    const f16* __restrict__ PW0, const f16* __restrict__ PW1, const f16* __restrict__ PWI1,
    const f16* __restrict__ WP0, const f16* __restrict__ xpad,
    const float* __restrict__ hidden_in,
    const float* __restrict__ bih0, const float* __restrict__ bhh0,
    const float* __restrict__ bih1, const float* __restrict__ bhh1,
    f16* __restrict__ Y0E, f16* __restrict__ Y1E,
    float* __restrict__ hT_out, int* __restrict__ cnt)
{
  extern __shared__ char smem[];
  char* WLb = smem;                // 96KB weight slice
  char* hSb = smem + 98304;        // 32KB h tile (swizzled)
  char* xSb = smem + 131072;       // 32KB y0 tile (swizzled, L1 only)

  const int tid = threadIdx.x, lane = tid & 63, wid = tid >> 6;
  const int colL = lane & 15, kgrp = lane >> 4;
  const bool isL1 = blockIdx.x >= 128;
  const int bid = blockIdx.x & 127;
  const int WGb = bid & 7, WGj = bid >> 3;
  const int bgl = wid & 1, jgl = wid >> 1;
  const int bgG = WGb * 2 + bgl;             // batch-16 group 0..15
  const int jgG = WGj * 2 + jgl;             // j-16 group 0..31
  const int bBase = WGb * 32;
  const int j = jgG * 16 + colL;
  const int arow = bgl * 16 + colL;
  const int asw = (colL & 7) << 4;

  f16* Yme = isL1 ? Y1E : Y0E;
  int* flag0 = cnt + WGb * 128;
  int* flagMe = flag0 + (isL1 ? 1024 : 0);

  // ---- WG's 96KB Whh slice -> LDS ----
  {
    const f16* wsrc = (isL1 ? PW1 : PW0) + (size_t)WGj * 96 * 512;
#pragma unroll
    for (int c = 0; c < 24; ++c) {
      int cid = tid + 256 * c;
      *(f16x8*)(WLb + (size_t)cid * 16) = *(const f16x8*)(wsrc + (size_t)cid * 8);
    }
  }

  // ---- biases (unified cell form) ----
  const float* bih = isL1 ? bih1 : bih0;
  const float* bhh = isL1 ? bhh1 : bhh0;
  const float bs_r = bih[j] + bhh[j];
  const float bs_z = bih[512 + j] + bhh[512 + j];
  const float b_in = bih[1024 + j];
  const float b_hn = bhh[1024 + j];

  float hreg[4];
#pragma unroll
  for (int i = 0; i < 4; ++i)
    hreg[i] = hidden_in[((size_t)(isL1 ? 1 : 0) * 256 + bgG * 16 + kgrp * 4 + i) * 512 + j];

  // ---- per-layer constant input weights ----
  f16x8 WIr[3];        // L0: padded K=8 input weights
  f16x8 xA;            // L0: current x fragment
  f16x8 WihV[48];      // L1: Wih1 slice, register-resident (192 VGPRs)
  if (isL1) {
#pragma unroll
    for (int f2 = 0; f2 < 48; ++f2)
      WihV[f2] = *(const f16x8*)(PWI1 + ((size_t)(jgG * 48 + f2) * 64 + lane) * 8);
  } else {
#pragma unroll
    for (int g = 0; g < 3; ++g)
      WIr[g] = *(const f16x8*)(WP0 + (((size_t)jgG * 3 + g) * 64 + lane) * 8);
    xA = *(const f16x8*)(xpad + ((size_t)bgG * 16 + colL) * 8);
  }

#pragma unroll 1
  for (int t = 0; t < 128; ++t) {
    // ---- acquire ----
    if (tid == 0) {
      if (isL1) spin_ge16(flag0 + t);            // y0(t) ready (slot t+1)
      if (t > 0) spin_ge16(flagMe + t - 1);      // own h(t) ready
    }
    __syncthreads();

    // ---- stage h(t) (and y0(t) for L1) into swizzled LDS via device-scope loads ----
    {
      const char* hb = (const char*)Yme + ((size_t)t * 256 + bBase) * 1024;
      f16x8 tmpH[8], tmpX[8];
#pragma unroll
      for (int s = 0; s < 8; ++s) {
        int cid = tid + 256 * s;
        tmpH[s] = load_b128_dev(hb + (size_t)(cid >> 6) * 1024 + (cid & 63) * 16);
      }
      if (isL1) {
        const char* xb = (const char*)Y0E + ((size_t)(t + 1) * 256 + bBase) * 1024;
#pragma unroll
        for (int s = 0; s < 8; ++s) {
          int cid = tid + 256 * s;
          tmpX[s] = load_b128_dev(xb + (size_t)(cid >> 6) * 1024 + (cid & 63) * 16);
        }
      }
      asm volatile("s_waitcnt vmcnt(0)" ::: "memory");
      __builtin_amdgcn_sched_barrier(0);
#pragma unroll
      for (int s = 0; s < 8; ++s) {
        int cid = tid + 256 * s;
        int row = cid >> 6, ch = cid & 63;
        *(f16x8*)(hSb + row * 1024 + ((ch * 16) ^ ((row & 7) << 4))) = tmpH[s];
      }
      if (isL1) {
#pragma unroll
        for (int s = 0; s < 8; ++s) {
          int cid = tid + 256 * s;
          int row = cid >> 6, ch = cid & 63;
          *(f16x8*)(xSb + row * 1024 + ((ch * 16) ^ ((row & 7) << 4))) = tmpX[s];
        }
      }
    }
    __syncthreads();   // tiles ready (t==0 also covers WL copy)

    // ---- MFMAs: h-part (LDS weights) + x-part (VGPR weights / L0 single tile) ----
    f32x4 ar, az, an_, ain;
#pragma unroll
    for (int q = 0; q < 4; ++q) { ar[q] = 0.f; az[q] = 0.f; an_[q] = 0.f; ain[q] = 0.f; }
#pragma unroll
    for (int kt = 0; kt < 16; ++kt) {
      f16x8 aF = *(const f16x8*)(hSb + arow * 1024 + ((kt * 64 + kgrp * 16) ^ asw));
      const char* wb = WLb + (size_t)(jgl * 48 + kt * 3) * 1024 + lane * 16;
      ar  = mfma16(aF, *(const f16x8*)(wb),        ar);
      az  = mfma16(aF, *(const f16x8*)(wb + 1024), az);
      an_ = mfma16(aF, *(const f16x8*)(wb + 2048), an_);
      if (isL1) {
        f16x8 aX = *(const f16x8*)(xSb + arow * 1024 + ((kt * 64 + kgrp * 16) ^ asw));
        ar  = mfma16(aX, WihV[kt * 3 + 0], ar);
        az  = mfma16(aX, WihV[kt * 3 + 1], az);
        ain = mfma16(aX, WihV[kt * 3 + 2], ain);
      }
    }
    if (!isL1) {
      ar  = mfma16(xA, WIr[0], ar);
      az  = mfma16(xA, WIr[1], az);
      ain = mfma16(xA, WIr[2], ain);
    }

    // ---- unified cell update; device-scope store of h(t+1) (= y[t]) ----
    {
      f16* yb = Yme + ((size_t)(t + 1) * 256 + bgG * 16 + kgrp * 4) * 512 + j;
#pragma unroll
      for (int i = 0; i < 4; ++i) {
        float r = sigm(ar[i] + bs_r);
        float z = sigm(az[i] + bs_z);
        float n = tanh_fast(ain[i] + b_in + r * (an_[i] + b_hn));
        float hnew = (1.f - z) * n + z * hreg[i];
        hreg[i] = hnew;
        store_f16_dev(yb + (size_t)i * 512, (f16)hnew);
      }
    }

    // ---- release ----
    asm volatile("s_waitcnt vmcnt(0)" ::: "memory");
    __syncthreads();
    if (tid == 0)
      __hip_atomic_fetch_add(&flagMe[t], 1, __ATOMIC_RELAXED, __HIP_MEMORY_SCOPE_AGENT);

    // ---- L0: prefetch next x fragment (overlaps next spin) ----
    if (!isL1)
      xA = *(const f16x8*)(xpad + ((size_t)((t + 1) & 127) * 256 + bgG * 16 + colL) * 8);
  }

  float* ht = hT_out + (isL1 ? 131072 : 0);
#pragma unroll
  for (int i = 0; i < 4; ++i)
    ht[((size_t)bgG * 16 + kgrp * 4 + i) * 512 + j] = hreg[i];
}

// ---------------- u = y1 @ Wlin^T + b_lin (fp32 out) ----------------
__global__ __launch_bounds__(256, 1) void gemm_u_k(
    const f16* __restrict__ A, const f16* __restrict__ B,
    const float* __restrict__ bias, float* __restrict__ C)
{
  const int lane = threadIdx.x & 63, wd = threadIdx.x >> 6;
  const int colL = lane & 15, kgrp = lane >> 4;
  const int m0 = blockIdx.x * 64;
  const int n0 = wd * 128;
  f32x4 acc[4][8];
#pragma unroll
  for (int a = 0; a < 4; ++a)
#pragma unroll
    for (int n = 0; n < 8; ++n)
#pragma unroll
      for (int q = 0; q < 4; ++q) acc[a][n][q] = 0.f;

  for (int kt = 0; kt < 16; ++kt) {
    f16x8 aF[4];
#pragma unroll
    for (int at = 0; at < 4; ++at)
      aF[at] = *(const f16x8*)(A + ((size_t)(m0 + at * 16 + colL)) * 512 + kt * 32 + kgrp * 8);
#pragma unroll
    for (int nt = 0; nt < 8; ++nt) {
      f16x8 bF = *(const f16x8*)(B + ((size_t)(n0 + nt * 16 + colL)) * 512 + kt * 32 + kgrp * 8);
#pragma unroll
      for (int at = 0; at < 4; ++at)
        acc[at][nt] = mfma16(aF[at], bF, acc[at][nt]);
    }
  }
#pragma unroll
  for (int nt = 0; nt < 8; ++nt) {
    int col = n0 + nt * 16 + colL;
    float bv = bias[col];
#pragma unroll
    for (int at = 0; at < 4; ++at)
#pragma unroll
      for (int i = 0; i < 4; ++i)
        C[((size_t)(m0 + at * 16 + kgrp * 4 + i)) * 512 + col] = acc[at][nt][i] + bv;
  }
}

// ---------------- normalization pass 1 ----------------
__global__ __launch_bounds__(256) void norm1_k(const float* __restrict__ U,
    float* __restrict__ dsuf, float* __restrict__ de, float* __restrict__ du)
{
  int id = blockIdx.x * 4 + (threadIdx.x >> 6);
  int lane = threadIdx.x & 63;
  int k = id >> 8;
  const float* row = U + (size_t)id * 512;
  f32x4 v0 = *(const f32x4*)(row + lane * 8);
  f32x4 v1 = *(const f32x4*)(row + lane * 8 + 4);
  float vals[8] = {v0[0], v0[1], v0[2], v0[3], v1[0], v1[1], v1[2], v1[3]};
  int j0 = lane * 8;
  float s = 0.f;
#pragma unroll
  for (int q = 0; q < 8; ++q) {
    float v = ((j0 + q) >= 4 * k) ? vals[q] : 0.f;
    s += v * v;
  }
#pragma unroll
  for (int off = 1; off < 64; off <<= 1) s += __shfl_xor(s, off);
  if (lane == (k >> 1)) {
    int o = (k & 1) * 4;
    float e = vals[o] * vals[o] + vals[o + 1] * vals[o + 1] +
              vals[o + 2] * vals[o + 2] + vals[o + 3] * vals[o + 3];
    de[id] = e; dsuf[id] = s;
    f32x4 d = {vals[o], vals[o + 1], vals[o + 2], vals[o + 3]};
    *(f32x4*)(du + (size_t)id * 4) = d;
  }
}

// ---------------- normalization pass 2 ----------------
__global__ __launch_bounds__(256) void norm2_k(const float* __restrict__ dsuf,
    const float* __restrict__ de, const float* __restrict__ du, float* __restrict__ out)
{
  int b = threadIdx.x;
  float L = 128.f;
  for (int kc = 0; kc < 8; ++kc) {
    float ss[16], ee[16]; f32x4 dd[16];
#pragma unroll
    for (int q = 0; q < 16; ++q) {
      int id = (kc * 16 + q) * 256 + b;
      ss[q] = dsuf[id]; ee[q] = de[id];
      dd[q] = *(const f32x4*)(du + (size_t)id * 4);
    }
#pragma unroll
    for (int q = 0; q < 16; ++q) {
      int id = (kc * 16 + q) * 256 + b;
      float sc = sqrtf(L / ss[q]);
      f32x4 o = dd[q];
      o[0] *= sc; o[1] *= sc; o[2] *= sc; o[3] *= sc;
      *(f32x4*)(out + (size_t)id * 4) = o;
      L *= (1.f - ee[q] / ss[q]);
    }
  }
}

// ---------------- launch ----------------
extern "C" void kernel_launch(void* const* d_in, const int* in_sizes, int n_in,
                              void* d_out, int out_size, void* d_ws, size_t ws_size,
                              hipStream_t stream) {
  (void)in_sizes; (void)n_in; (void)out_size; (void)ws_size;
  const float* pn   = (const float*)d_in[0];
  const float* mn   = (const float*)d_in[1];
  const float* hid  = (const float*)d_in[2];
  const float* Wih0 = (const float*)d_in[3];
  const float* Whh0 = (const float*)d_in[4];
  const float* bih0 = (const float*)d_in[5];
  const float* bhh0 = (const float*)d_in[6];
  const float* Wih1 = (const float*)d_in[7];
  const float* Whh1 = (const float*)d_in[8];
  const float* bih1 = (const float*)d_in[9];
  const float* bhh1 = (const float*)d_in[10];
  const float* Wlin = (const float*)d_in[11];
  const float* blin = (const float*)d_in[12];
  float* out = (float*)d_out;
  char* ws = (char*)d_ws;

  f16* PW0  = (f16*)(ws + OFF_PW0);
  f16* PW1  = (f16*)(ws + OFF_PW1);
  f16* PWI1 = (f16*)(ws + OFF_PWI1);
  f16* WLIN = (f16*)(ws + OFF_WLIN);
  f16* WP0  = (f16*)(ws + OFF_WP0);
  f16* XPAD = (f16*)(ws + OFF_XPAD);
  int* CNT  = (int*)(ws + OFF_CNT);
  f16* Y0E  = (f16*)(ws + OFF_Y0E);
  f16* Y1E  = (f16*)(ws + OFF_Y1E);
  float* U  = (float*)(ws + OFF_U);
  float* DSUF = (float*)(ws + OFF_DIAG);
  float* DE   = (float*)(ws + OFF_DIAG + 131072);
  float* DU   = (float*)(ws + OFF_DIAG + 262144);

  hipFuncSetAttribute(reinterpret_cast<const void*>(gru_fused_k),
                      hipFuncAttributeMaxDynamicSharedMemorySize, 163840);

  prep_pack_k<<<1152, 256, 0, stream>>>(Whh0, Whh1, Wih1, PW0, PW1, PWI1);
  prep_misc_k<<<1312, 256, 0, stream>>>(Wlin, Wih0, pn, mn, hid,
                                        WLIN, WP0, XPAD, Y0E, Y1E, CNT);
  gru_fused_k<<<256, 256, 163840, stream>>>(PW0, PW1, PWI1, WP0, XPAD, hid,
                                            bih0, bhh0, bih1, bhh1,
                                            Y0E, Y1E, out + 131072, CNT);
  gemm_u_k<<<512, 256, 0, stream>>>(Y1E + 131072, WLIN, blin, U);
  norm1_k<<<8192, 256, 0, stream>>>(U, DSUF, DE, DU);
  norm2_k<<<1, 256, 0, stream>>>(DSUF, DE, DU, out);
}